// Round 1
// baseline (658.479 us; speedup 1.0000x reference)
//
#include <hip/hip_runtime.h>

typedef __bf16 bf16_t;
typedef bf16_t bf16x8 __attribute__((ext_vector_type(8)));
typedef float f32x4 __attribute__((ext_vector_type(4)));

constexpr int BATCH = 4, SEQ = 2048, CH = 1024, NHEAD = 16, HD = 64;
constexpr int BM = 128, BN = 128, BKK = 32;

__device__ __forceinline__ void g2lds16(const bf16_t* g, bf16_t* l) {
  __builtin_amdgcn_global_load_lds((__attribute__((address_space(1))) void*)(g),
                                   (__attribute__((address_space(3))) void*)(l),
                                   16, 0, 0);
}

__device__ __forceinline__ f32x4 mfma16(bf16x8 a, bf16x8 b, f32x4 c) {
  return __builtin_amdgcn_mfma_f32_16x16x32_bf16(a, b, c, 0, 0, 0);
}

// ---------------- fp32 -> bf16 conversion ----------------
__global__ __launch_bounds__(256) void cvt_kernel(const float4* __restrict__ src,
                                                  ushort4* __restrict__ dst, int n4) {
  int i = blockIdx.x * 256 + threadIdx.x;
  if (i >= n4) return;
  float4 f = src[i];
  ushort4 o;
  o.x = __builtin_bit_cast(unsigned short, (bf16_t)f.x);
  o.y = __builtin_bit_cast(unsigned short, (bf16_t)f.y);
  o.z = __builtin_bit_cast(unsigned short, (bf16_t)f.z);
  o.w = __builtin_bit_cast(unsigned short, (bf16_t)f.w);
  dst[i] = o;
}

// ---------------- shared GEMM mainloop (C = A * W^T), m97 pattern ----------------
// Block 128x128, 4 waves in 2x2 of 64x64, 16x16x32 bf16 MFMA, BK=32.
__device__ __forceinline__ void gemm_mainloop(const bf16_t* __restrict__ A,
                                              const bf16_t* __restrict__ W, int Kdim,
                                              int m0, int n0,
                                              bf16_t* As, bf16_t* Bs,
                                              f32x4 acc[4][4]) {
  const int tid = threadIdx.x;
  const int lane = tid & 63, w = tid >> 6;
  const int quad = lane >> 4, l16 = lane & 15;
  const int wm = (w >> 1) << 6, wn = (w & 1) << 6;
  const int srow = (w << 5) + (lane >> 2);   // staging row 0..127 (w*32 + lane/4)
  const int scol = (lane & 3) << 3;          // staging col (elements)
  const bf16_t* ga0 = A + (size_t)(m0 + srow) * Kdim + scol;
  const bf16_t* ga1 = A + (size_t)(m0 + srow + 16) * Kdim + scol;
  const bf16_t* gb0 = W + (size_t)(n0 + srow) * Kdim + scol;
  const bf16_t* gb1 = W + (size_t)(n0 + srow + 16) * Kdim + scol;
  bf16_t* la0 = As + srow * BKK + scol;
  bf16_t* la1 = As + (srow + 16) * BKK + scol;
  bf16_t* lb0 = Bs + srow * BKK + scol;
  bf16_t* lb1 = Bs + (srow + 16) * BKK + scol;
  for (int k0 = 0; k0 < Kdim; k0 += BKK) {
    g2lds16(ga0 + k0, la0);
    g2lds16(ga1 + k0, la1);
    g2lds16(gb0 + k0, lb0);
    g2lds16(gb1 + k0, lb1);
    __syncthreads();
    bf16x8 av[4], bv[4];
#pragma unroll
    for (int i = 0; i < 4; i++)
      av[i] = *(const bf16x8*)&As[(wm + i * 16 + l16) * BKK + quad * 8];
#pragma unroll
    for (int i = 0; i < 4; i++)
      bv[i] = *(const bf16x8*)&Bs[(wn + i * 16 + l16) * BKK + quad * 8];
#pragma unroll
    for (int mi = 0; mi < 4; mi++)
#pragma unroll
      for (int ni = 0; ni < 4; ni++)
        acc[mi][ni] = mfma16(av[mi], bv[ni], acc[mi][ni]);
    __syncthreads();
  }
}

// ---------------- QKV GEMM + bias + RoPE + scatter (Q,K row-major; V transposed) ----
__global__ __launch_bounds__(256) void qkv_rope_kernel(
    const bf16_t* __restrict__ X, const bf16_t* __restrict__ Wa,
    const float* __restrict__ ba, const float* __restrict__ cosT,
    const float* __restrict__ sinT, bf16_t* __restrict__ Q,
    bf16_t* __restrict__ Ko, bf16_t* __restrict__ VT) {
  constexpr int TSTRIDE = 68;                      // transpose row stride (bank spread)
  __shared__ __align__(16) char smem[4 * 64 * TSTRIDE * 2];  // 34816 B >= 16 KiB staging
  bf16_t* As = (bf16_t*)smem;
  bf16_t* Bs = As + BM * BKK;

  f32x4 acc[4][4];
#pragma unroll
  for (int i = 0; i < 4; i++)
#pragma unroll
    for (int j = 0; j < 4; j++) acc[i][j] = (f32x4){0.f, 0.f, 0.f, 0.f};

  const int n0 = blockIdx.x * BN, m0 = blockIdx.y * BM;
  gemm_mainloop(X, Wa, CH, m0, n0, As, Bs, acc);

  const int tid = threadIdx.x, lane = tid & 63, w = tid >> 6;
  const int quad = lane >> 4, l16 = lane & 15;
  const int wm = (w >> 1) << 6, wn = (w & 1) << 6;
  const int nbase = n0 + wn;                 // 64-aligned -> single (part, head)
  const int part = nbase >> 10;              // 0=q 1=k 2=v
  const int h = (nbase & 1023) >> 6;
  const int mbase = m0 + wm;
  const int bb = mbase >> 11;                // batch (block never straddles)
  const size_t headbase = ((size_t)(bb * NHEAD + h)) * SEQ * HD;

  if (part < 2) {
    bf16_t* O = (part == 0) ? Q : Ko;
#pragma unroll
    for (int mi = 0; mi < 4; mi++)
#pragma unroll
      for (int r = 0; r < 4; r++) {
        int m = mbase + mi * 16 + quad * 4 + r;
        int t = m & (SEQ - 1);
        const float* cr = cosT + t * HD;
        const float* sr = sinT + t * HD;
        size_t rowo = headbase + (size_t)t * HD;
#pragma unroll
        for (int ni = 0; ni < 2; ni++) {
          int d0 = ni * 16 + l16, d1 = d0 + 32;
          float v0 = acc[mi][ni][r] + ba[nbase + d0];
          float v1 = acc[mi][ni + 2][r] + ba[nbase + d1];
          float r0 = v0 * cr[d0] - v1 * sr[d0];
          float r1 = v1 * cr[d1] + v0 * sr[d1];
          O[rowo + d0] = (bf16_t)r0;
          O[rowo + d1] = (bf16_t)r1;
        }
      }
  } else {
    // V: per-wave LDS transpose -> VT[bh][d][t] for contiguous PV B-fragments
    bf16_t* tb = (bf16_t*)smem + w * 64 * TSTRIDE;
    int t0 = mbase & (SEQ - 1);
#pragma unroll
    for (int mi = 0; mi < 4; mi++)
#pragma unroll
      for (int ni = 0; ni < 4; ni++) {
        int d = ni * 16 + l16;
        float bias = ba[nbase + d];
#pragma unroll
        for (int r = 0; r < 4; r++) {
          float v = acc[mi][ni][r] + bias;
          tb[d * TSTRIDE + mi * 16 + quad * 4 + r] = (bf16_t)v;
        }
      }
    __builtin_amdgcn_s_waitcnt(0xc07f);  // lgkmcnt(0): same-wave LDS RAW
    int half = lane >> 5, l5 = lane & 31;
    size_t vbase = ((size_t)(bb * NHEAD + h)) * HD * SEQ;
#pragma unroll
    for (int it = 0; it < 32; it++) {
      int d = it * 2 + half;
      unsigned int val = *(const unsigned int*)&tb[d * TSTRIDE + l5 * 2];
      *(unsigned int*)&VT[vbase + (size_t)d * SEQ + t0 + l5 * 2] = val;
    }
  }
}

// ---------------- flash attention: wave = 16 q-rows, K-chunks of 32 ----------------
__global__ __launch_bounds__(256) void flash_kernel(const bf16_t* __restrict__ Q,
                                                    const bf16_t* __restrict__ Kg,
                                                    const bf16_t* __restrict__ VT,
                                                    bf16_t* __restrict__ att) {
  __shared__ bf16_t Pb[4 * 512];  // per-wave 16x32 bf16 P buffer
  const int tid = threadIdx.x, w = tid >> 6, lane = tid & 63;
  const int quad = lane >> 4, l16 = lane & 15;
  const int bh = blockIdx.y;
  const int qt0 = blockIdx.x * 64 + w * 16;
  const bf16_t* Qb = Q + (size_t)bh * SEQ * HD;
  const bf16_t* Kb = Kg + (size_t)bh * SEQ * HD;
  const bf16_t* Vb = VT + (size_t)bh * HD * SEQ;

  bf16x8 aq0 = *(const bf16x8*)&Qb[(size_t)(qt0 + l16) * HD + quad * 8];
  bf16x8 aq1 = *(const bf16x8*)&Qb[(size_t)(qt0 + l16) * HD + 32 + quad * 8];

  float mrun[4], lrun[4];
  f32x4 yacc[4];
#pragma unroll
  for (int r = 0; r < 4; r++) { mrun[r] = -1e30f; lrun[r] = 0.f; }
#pragma unroll
  for (int ni = 0; ni < 4; ni++) yacc[ni] = (f32x4){0.f, 0.f, 0.f, 0.f};

  bf16_t* pb = Pb + w * 512;
  const int kend = qt0 + 16;
  for (int kc = 0; kc < kend; kc += 32) {
    f32x4 s0 = (f32x4){0.f, 0.f, 0.f, 0.f};
    f32x4 s1 = (f32x4){0.f, 0.f, 0.f, 0.f};
    const bf16_t* kp0 = &Kb[(size_t)(kc + l16) * HD + quad * 8];
    const bf16_t* kp1 = &Kb[(size_t)(kc + 16 + l16) * HD + quad * 8];
    s0 = mfma16(aq0, *(const bf16x8*)kp0, s0);
    s0 = mfma16(aq1, *(const bf16x8*)(kp0 + 32), s0);
    s1 = mfma16(aq0, *(const bf16x8*)kp1, s1);
    s1 = mfma16(aq1, *(const bf16x8*)(kp1 + 32), s1);
    s0 *= 0.125f;
    s1 *= 0.125f;
    if (kc + 31 > qt0) {  // diagonal chunk: causal mask
#pragma unroll
      for (int r = 0; r < 4; r++) {
        int row = qt0 + quad * 4 + r;
        if (kc + l16 > row) s0[r] = -1e30f;
        if (kc + 16 + l16 > row) s1[r] = -1e30f;
      }
    }
#pragma unroll
    for (int r = 0; r < 4; r++) {
      float mc = fmaxf(s0[r], s1[r]);
      mc = fmaxf(mc, __shfl_xor(mc, 1));
      mc = fmaxf(mc, __shfl_xor(mc, 2));
      mc = fmaxf(mc, __shfl_xor(mc, 4));
      mc = fmaxf(mc, __shfl_xor(mc, 8));
      float mn = fmaxf(mrun[r], mc);
      float alpha = __expf(mrun[r] - mn);
      mrun[r] = mn;
      float p0 = __expf(s0[r] - mn);
      float p1 = __expf(s1[r] - mn);
      s0[r] = p0; s1[r] = p1;
      float lc = p0 + p1;
      lc += __shfl_xor(lc, 1);
      lc += __shfl_xor(lc, 2);
      lc += __shfl_xor(lc, 4);
      lc += __shfl_xor(lc, 8);
      lrun[r] = lrun[r] * alpha + lc;
#pragma unroll
      for (int ni = 0; ni < 4; ni++) yacc[ni][r] *= alpha;
    }
    // P (C-layout) -> LDS -> A-layout fragment
#pragma unroll
    for (int r = 0; r < 4; r++) {
      pb[(quad * 4 + r) * 32 + l16] = (bf16_t)s0[r];
      pb[(quad * 4 + r) * 32 + 16 + l16] = (bf16_t)s1[r];
    }
    __builtin_amdgcn_s_waitcnt(0xc07f);  // lgkmcnt(0): same-wave LDS RAW
    bf16x8 pf = *(const bf16x8*)&pb[l16 * 32 + quad * 8];
    const bf16_t* vp = Vb + kc + quad * 8;
#pragma unroll
    for (int ni = 0; ni < 4; ni++) {
      bf16x8 bv = *(const bf16x8*)&vp[(size_t)(ni * 16 + l16) * SEQ];
      yacc[ni] = mfma16(pf, bv, yacc[ni]);
    }
  }

  const int bloc = bh >> 4, hh = bh & 15;
#pragma unroll
  for (int r = 0; r < 4; r++) {
    float inv = 1.0f / lrun[r];
    int t = qt0 + quad * 4 + r;
    size_t rowbase = ((size_t)bloc * SEQ + t) * CH + hh * HD;
#pragma unroll
    for (int ni = 0; ni < 4; ni++)
      att[rowbase + ni * 16 + l16] = (bf16_t)(yacc[ni][r] * inv);
  }
}

// ---------------- output projection GEMM, fp32 out + bias ----------------
__global__ __launch_bounds__(256) void proj_kernel(const bf16_t* __restrict__ A,
                                                   const bf16_t* __restrict__ Wp,
                                                   const float* __restrict__ bp,
                                                   float* __restrict__ out) {
  __shared__ __align__(16) bf16_t As[BM * BKK];
  __shared__ __align__(16) bf16_t Bs[BN * BKK];
  f32x4 acc[4][4];
#pragma unroll
  for (int i = 0; i < 4; i++)
#pragma unroll
    for (int j = 0; j < 4; j++) acc[i][j] = (f32x4){0.f, 0.f, 0.f, 0.f};
  const int n0 = blockIdx.x * BN, m0 = blockIdx.y * BM;
  gemm_mainloop(A, Wp, CH, m0, n0, As, Bs, acc);
  const int tid = threadIdx.x, lane = tid & 63, w = tid >> 6;
  const int quad = lane >> 4, l16 = lane & 15;
  const int wm = (w >> 1) << 6, wn = (w & 1) << 6;
  const int nbase = n0 + wn, mbase = m0 + wm;
#pragma unroll
  for (int mi = 0; mi < 4; mi++)
#pragma unroll
    for (int r = 0; r < 4; r++) {
      int m = mbase + mi * 16 + quad * 4 + r;
#pragma unroll
      for (int ni = 0; ni < 4; ni++) {
        int n = nbase + ni * 16 + l16;
        out[(size_t)m * CH + n] = acc[mi][ni][r] + bp[n];
      }
    }
}

extern "C" void kernel_launch(void* const* d_in, const int* in_sizes, int n_in,
                              void* d_out, int out_size, void* d_ws, size_t ws_size,
                              hipStream_t stream) {
  const float* x      = (const float*)d_in[0];
  const float* w_attn = (const float*)d_in[1];
  const float* b_attn = (const float*)d_in[2];
  const float* w_proj = (const float*)d_in[3];
  const float* b_proj = (const float*)d_in[4];
  const float* cosT   = (const float*)d_in[5];
  const float* sinT   = (const float*)d_in[6];
  float* out = (float*)d_out;

  bf16_t* xbf  = (bf16_t*)d_ws;
  bf16_t* wabf = xbf + (size_t)8192 * 1024;
  bf16_t* wpbf = wabf + (size_t)3072 * 1024;
  bf16_t* Qb   = wpbf + (size_t)1024 * 1024;
  bf16_t* Kb   = Qb + (size_t)8388608;
  bf16_t* VTb  = Kb + (size_t)8388608;
  bf16_t* attb = VTb + (size_t)8388608;

  cvt_kernel<<<8192, 256, 0, stream>>>((const float4*)x, (ushort4*)xbf, 2097152);
  cvt_kernel<<<3072, 256, 0, stream>>>((const float4*)w_attn, (ushort4*)wabf, 786432);
  cvt_kernel<<<1024, 256, 0, stream>>>((const float4*)w_proj, (ushort4*)wpbf, 262144);
  qkv_rope_kernel<<<dim3(24, 64), 256, 0, stream>>>(xbf, wabf, b_attn, cosT, sinT,
                                                    Qb, Kb, VTb);
  flash_kernel<<<dim3(32, 64), 256, 0, stream>>>(Qb, Kb, VTb, attb);
  proj_kernel<<<dim3(8, 64), 256, 0, stream>>>(attb, wpbf, b_proj, out);
}

// Round 2
// 458.215 us; speedup vs baseline: 1.4371x; 1.4371x over previous
//
#include <hip/hip_runtime.h>

typedef __bf16 bf16_t;
typedef bf16_t bf16x8 __attribute__((ext_vector_type(8)));
typedef float f32x4 __attribute__((ext_vector_type(4)));

constexpr int BATCH = 4, SEQ = 2048, CH = 1024, NHEAD = 16, HD = 64;
constexpr int BM = 128, BN = 128, BKK = 32;

__device__ __forceinline__ void g2lds16(const bf16_t* g, bf16_t* l) {
  __builtin_amdgcn_global_load_lds((__attribute__((address_space(1))) void*)(g),
                                   (__attribute__((address_space(3))) void*)(l),
                                   16, 0, 0);
}

__device__ __forceinline__ f32x4 mfma16(bf16x8 a, bf16x8 b, f32x4 c) {
  return __builtin_amdgcn_mfma_f32_16x16x32_bf16(a, b, c, 0, 0, 0);
}

// ---------------- fp32 -> bf16 conversion ----------------
__global__ __launch_bounds__(256) void cvt_kernel(const float4* __restrict__ src,
                                                  ushort4* __restrict__ dst, int n4) {
  int i = blockIdx.x * 256 + threadIdx.x;
  if (i >= n4) return;
  float4 f = src[i];
  ushort4 o;
  o.x = __builtin_bit_cast(unsigned short, (bf16_t)f.x);
  o.y = __builtin_bit_cast(unsigned short, (bf16_t)f.y);
  o.z = __builtin_bit_cast(unsigned short, (bf16_t)f.z);
  o.w = __builtin_bit_cast(unsigned short, (bf16_t)f.w);
  dst[i] = o;
}

// ---------------- shared GEMM mainloop (C = A * W^T), m97 pattern ----------------
__device__ __forceinline__ void gemm_mainloop(const bf16_t* __restrict__ A,
                                              const bf16_t* __restrict__ W, int Kdim,
                                              int m0, int n0,
                                              bf16_t* As, bf16_t* Bs,
                                              f32x4 acc[4][4]) {
  const int tid = threadIdx.x;
  const int lane = tid & 63, w = tid >> 6;
  const int quad = lane >> 4, l16 = lane & 15;
  const int wm = (w >> 1) << 6, wn = (w & 1) << 6;
  const int srow = (w << 5) + (lane >> 2);
  const int scol = (lane & 3) << 3;
  const bf16_t* ga0 = A + (size_t)(m0 + srow) * Kdim + scol;
  const bf16_t* ga1 = A + (size_t)(m0 + srow + 16) * Kdim + scol;
  const bf16_t* gb0 = W + (size_t)(n0 + srow) * Kdim + scol;
  const bf16_t* gb1 = W + (size_t)(n0 + srow + 16) * Kdim + scol;
  bf16_t* la0 = As + srow * BKK + scol;
  bf16_t* la1 = As + (srow + 16) * BKK + scol;
  bf16_t* lb0 = Bs + srow * BKK + scol;
  bf16_t* lb1 = Bs + (srow + 16) * BKK + scol;
  for (int k0 = 0; k0 < Kdim; k0 += BKK) {
    g2lds16(ga0 + k0, la0);
    g2lds16(ga1 + k0, la1);
    g2lds16(gb0 + k0, lb0);
    g2lds16(gb1 + k0, lb1);
    __syncthreads();
    bf16x8 av[4], bv[4];
#pragma unroll
    for (int i = 0; i < 4; i++)
      av[i] = *(const bf16x8*)&As[(wm + i * 16 + l16) * BKK + quad * 8];
#pragma unroll
    for (int i = 0; i < 4; i++)
      bv[i] = *(const bf16x8*)&Bs[(wn + i * 16 + l16) * BKK + quad * 8];
#pragma unroll
    for (int mi = 0; mi < 4; mi++)
#pragma unroll
      for (int ni = 0; ni < 4; ni++)
        acc[mi][ni] = mfma16(av[mi], bv[ni], acc[mi][ni]);
    __syncthreads();
  }
}

// ---------------- QKV GEMM + bias + RoPE + scatter ----------------
__global__ __launch_bounds__(256) void qkv_rope_kernel(
    const bf16_t* __restrict__ X, const bf16_t* __restrict__ Wa,
    const float* __restrict__ ba, const float* __restrict__ cosT,
    const float* __restrict__ sinT, bf16_t* __restrict__ Q,
    bf16_t* __restrict__ Ko, bf16_t* __restrict__ VT) {
  constexpr int TSTRIDE = 68;
  __shared__ __align__(16) char smem[4 * 64 * TSTRIDE * 2];
  bf16_t* As = (bf16_t*)smem;
  bf16_t* Bs = As + BM * BKK;

  f32x4 acc[4][4];
#pragma unroll
  for (int i = 0; i < 4; i++)
#pragma unroll
    for (int j = 0; j < 4; j++) acc[i][j] = (f32x4){0.f, 0.f, 0.f, 0.f};

  const int n0 = blockIdx.x * BN, m0 = blockIdx.y * BM;
  gemm_mainloop(X, Wa, CH, m0, n0, As, Bs, acc);

  const int tid = threadIdx.x, lane = tid & 63, w = tid >> 6;
  const int quad = lane >> 4, l16 = lane & 15;
  const int wm = (w >> 1) << 6, wn = (w & 1) << 6;
  const int nbase = n0 + wn;
  const int part = nbase >> 10;
  const int h = (nbase & 1023) >> 6;
  const int mbase = m0 + wm;
  const int bb = mbase >> 11;
  const size_t headbase = ((size_t)(bb * NHEAD + h)) * SEQ * HD;

  if (part < 2) {
    bf16_t* O = (part == 0) ? Q : Ko;
#pragma unroll
    for (int mi = 0; mi < 4; mi++)
#pragma unroll
      for (int r = 0; r < 4; r++) {
        int m = mbase + mi * 16 + quad * 4 + r;
        int t = m & (SEQ - 1);
        const float* cr = cosT + t * HD;
        const float* sr = sinT + t * HD;
        size_t rowo = headbase + (size_t)t * HD;
#pragma unroll
        for (int ni = 0; ni < 2; ni++) {
          int d0 = ni * 16 + l16, d1 = d0 + 32;
          float v0 = acc[mi][ni][r] + ba[nbase + d0];
          float v1 = acc[mi][ni + 2][r] + ba[nbase + d1];
          float r0 = v0 * cr[d0] - v1 * sr[d0];
          float r1 = v1 * cr[d1] + v0 * sr[d1];
          O[rowo + d0] = (bf16_t)r0;
          O[rowo + d1] = (bf16_t)r1;
        }
      }
  } else {
    bf16_t* tb = (bf16_t*)smem + w * 64 * TSTRIDE;
    int t0 = mbase & (SEQ - 1);
#pragma unroll
    for (int mi = 0; mi < 4; mi++)
#pragma unroll
      for (int ni = 0; ni < 4; ni++) {
        int d = ni * 16 + l16;
        float bias = ba[nbase + d];
#pragma unroll
        for (int r = 0; r < 4; r++) {
          float v = acc[mi][ni][r] + bias;
          tb[d * TSTRIDE + mi * 16 + quad * 4 + r] = (bf16_t)v;
        }
      }
    __builtin_amdgcn_s_waitcnt(0xc07f);
    int half = lane >> 5, l5 = lane & 31;
    size_t vbase = ((size_t)(bb * NHEAD + h)) * HD * SEQ;
#pragma unroll
    for (int it = 0; it < 32; it++) {
      int d = it * 2 + half;
      unsigned int val = *(const unsigned int*)&tb[d * TSTRIDE + l5 * 2];
      *(unsigned int*)&VT[vbase + (size_t)d * SEQ + t0 + l5 * 2] = val;
    }
  }
}

// ---------------- flash attention v2 ----------------
// Block = 128 q-rows; wave w owns m-tiles at w*16 and 64+w*16 (diagonal balance).
// K-chunk = 64, K/V^T double-buffered in LDS via global_load_lds w/ XOR swizzle.
constexpr int PSTR = 72;
constexpr float SCL = 0.125f * 1.44269504089f;  // 1/sqrt(64) * log2(e)

__device__ __forceinline__ void sm_update(f32x4 (&s)[4], float (&mr)[4], float (&lr)[4],
                                          f32x4 (&y)[4], int rowb, int kc, int l16,
                                          int quad, bool domask) {
  if (domask) {
#pragma unroll
    for (int r = 0; r < 4; r++) {
      int row = rowb + quad * 4 + r;
#pragma unroll
      for (int ni = 0; ni < 4; ni++)
        if (kc + ni * 16 + l16 > row) s[ni][r] = -1e30f;
    }
  }
#pragma unroll
  for (int r = 0; r < 4; r++) {
    float cm = fmaxf(fmaxf(s[0][r], s[1][r]), fmaxf(s[2][r], s[3][r]));
    cm = fmaxf(cm, __shfl_xor(cm, 1));
    cm = fmaxf(cm, __shfl_xor(cm, 2));
    cm = fmaxf(cm, __shfl_xor(cm, 4));
    cm = fmaxf(cm, __shfl_xor(cm, 8));
    float mn = fmaxf(mr[r], cm);
    float al = __builtin_exp2f(mr[r] - mn);
    mr[r] = mn;
    float p0 = __builtin_exp2f(s[0][r] - mn);
    float p1 = __builtin_exp2f(s[1][r] - mn);
    float p2 = __builtin_exp2f(s[2][r] - mn);
    float p3 = __builtin_exp2f(s[3][r] - mn);
    s[0][r] = p0; s[1][r] = p1; s[2][r] = p2; s[3][r] = p3;
    lr[r] = lr[r] * al + ((p0 + p1) + (p2 + p3));
    y[0][r] *= al; y[1][r] *= al; y[2][r] *= al; y[3][r] *= al;
  }
}

__global__ __launch_bounds__(256) void flash_kernel(const bf16_t* __restrict__ Q,
                                                    const bf16_t* __restrict__ Kg,
                                                    const bf16_t* __restrict__ VT,
                                                    bf16_t* __restrict__ att) {
  __shared__ __align__(16) bf16_t Ks[2][64 * 64];
  __shared__ __align__(16) bf16_t Vs[2][64 * 64];
  __shared__ __align__(16) bf16_t Pb[4][32 * PSTR];
  const int tid = threadIdx.x, w = tid >> 6, lane = tid & 63;
  const int quad = lane >> 4, l16 = lane & 15;
  const int bh = blockIdx.y;
  const int qb = (int)gridDim.x - 1 - (int)blockIdx.x;  // heavy blocks first
  const int mA = qb * 128 + w * 16;
  const int mB = mA + 64;
  const bf16_t* Qp = Q + (size_t)bh * SEQ * HD;
  const bf16_t* Kb = Kg + (size_t)bh * SEQ * HD;
  const bf16_t* Vb = VT + (size_t)bh * HD * SEQ;

  bf16x8 aqA0 = *(const bf16x8*)&Qp[(size_t)(mA + l16) * HD + quad * 8];
  bf16x8 aqA1 = *(const bf16x8*)&Qp[(size_t)(mA + l16) * HD + 32 + quad * 8];
  bf16x8 aqB0 = *(const bf16x8*)&Qp[(size_t)(mB + l16) * HD + quad * 8];
  bf16x8 aqB1 = *(const bf16x8*)&Qp[(size_t)(mB + l16) * HD + 32 + quad * 8];

  float mrA[4], lrA[4], mrB[4], lrB[4];
  f32x4 yA[4], yB[4];
#pragma unroll
  for (int r = 0; r < 4; r++) { mrA[r] = -1e30f; lrA[r] = 0.f; mrB[r] = -1e30f; lrB[r] = 0.f; }
#pragma unroll
  for (int ni = 0; ni < 4; ni++) { yA[ni] = (f32x4){0,0,0,0}; yB[ni] = (f32x4){0,0,0,0}; }

  // staging lane mapping: block (row d, jglobal) -> LDS block d*8 + (jglobal ^ (d&7))
  const int grow = lane >> 3;              // 0..7
  const int gj8 = ((lane & 7) ^ grow) * 8; // element offset of swizzled block
  const int i0 = w * 2;

  auto stage = [&](int kcs, int b) {
#pragma unroll
    for (int ii = 0; ii < 2; ii++) {
      int i = i0 + ii;
      g2lds16(Kb + (size_t)(kcs + i * 8 + grow) * HD + gj8, &Ks[b][(i * 64 + lane) * 8]);
      g2lds16(Vb + (size_t)(i * 8 + grow) * SEQ + kcs + gj8, &Vs[b][(i * 64 + lane) * 8]);
    }
  };

  const int nch = 2 * qb + 2;
  stage(0, 0);
  __syncthreads();

  const int sw = l16 & 7;  // read-side swizzle key
  for (int c = 0; c < nch; ++c) {
    const int kc = c * 64;
    const int buf = c & 1;
    if (c + 1 < nch) stage((c + 1) * 64, buf ^ 1);

    const bool doA = (kc <= mA + 15);
    f32x4 sA[4], sB[4];
#pragma unroll
    for (int ni = 0; ni < 4; ni++) {
      bf16x8 bk0 = *(const bf16x8*)&Ks[buf][((ni * 16 + l16) * 8 + (quad ^ sw)) * 8];
      bf16x8 bk1 = *(const bf16x8*)&Ks[buf][((ni * 16 + l16) * 8 + ((4 + quad) ^ sw)) * 8];
      f32x4 z = (f32x4){0, 0, 0, 0};
      sB[ni] = mfma16(aqB1, bk1, mfma16(aqB0, bk0, z));
      if (doA) sA[ni] = mfma16(aqA1, bk1, mfma16(aqA0, bk0, z));
    }
#pragma unroll
    for (int ni = 0; ni < 4; ni++) sB[ni] *= SCL;
    sm_update(sB, mrB, lrB, yB, mB, kc, l16, quad, kc + 63 > mB);
    if (doA) {
#pragma unroll
      for (int ni = 0; ni < 4; ni++) sA[ni] *= SCL;
      sm_update(sA, mrA, lrA, yA, mA, kc, l16, quad, kc + 63 > mA);
    }

    // P (C-layout) -> LDS (stride 72) -> A-layout frags
#pragma unroll
    for (int ni = 0; ni < 4; ni++)
#pragma unroll
      for (int r = 0; r < 4; r++) {
        Pb[w][(16 + quad * 4 + r) * PSTR + ni * 16 + l16] = (bf16_t)sB[ni][r];
        if (doA) Pb[w][(quad * 4 + r) * PSTR + ni * 16 + l16] = (bf16_t)sA[ni][r];
      }
    __builtin_amdgcn_s_waitcnt(0xc07f);  // lgkmcnt(0): same-wave LDS RAW

    bf16x8 paB0 = *(const bf16x8*)&Pb[w][(16 + l16) * PSTR + quad * 8];
    bf16x8 paB1 = *(const bf16x8*)&Pb[w][(16 + l16) * PSTR + 32 + quad * 8];
    bf16x8 paA0, paA1;
    if (doA) {
      paA0 = *(const bf16x8*)&Pb[w][l16 * PSTR + quad * 8];
      paA1 = *(const bf16x8*)&Pb[w][l16 * PSTR + 32 + quad * 8];
    }
#pragma unroll
    for (int ni = 0; ni < 4; ni++) {
      bf16x8 bv0 = *(const bf16x8*)&Vs[buf][((ni * 16 + l16) * 8 + (quad ^ sw)) * 8];
      bf16x8 bv1 = *(const bf16x8*)&Vs[buf][((ni * 16 + l16) * 8 + ((4 + quad) ^ sw)) * 8];
      yB[ni] = mfma16(paB1, bv1, mfma16(paB0, bv0, yB[ni]));
      if (doA) yA[ni] = mfma16(paA1, bv1, mfma16(paA0, bv0, yA[ni]));
    }
    __syncthreads();
  }

  const int bloc = bh >> 4, hh = bh & 15;
#pragma unroll
  for (int r = 0; r < 4; r++) {
    float lA = lrA[r], lB = lrB[r];
    lA += __shfl_xor(lA, 1); lA += __shfl_xor(lA, 2);
    lA += __shfl_xor(lA, 4); lA += __shfl_xor(lA, 8);
    lB += __shfl_xor(lB, 1); lB += __shfl_xor(lB, 2);
    lB += __shfl_xor(lB, 4); lB += __shfl_xor(lB, 8);
    float invA = 1.0f / lA, invB = 1.0f / lB;
    int tA = mA + quad * 4 + r, tB = mB + quad * 4 + r;
    size_t rbA = ((size_t)bloc * SEQ + tA) * CH + hh * HD;
    size_t rbB = ((size_t)bloc * SEQ + tB) * CH + hh * HD;
#pragma unroll
    for (int ni = 0; ni < 4; ni++) {
      att[rbA + ni * 16 + l16] = (bf16_t)(yA[ni][r] * invA);
      att[rbB + ni * 16 + l16] = (bf16_t)(yB[ni][r] * invB);
    }
  }
}

// ---------------- output projection GEMM ----------------
__global__ __launch_bounds__(256) void proj_kernel(const bf16_t* __restrict__ A,
                                                   const bf16_t* __restrict__ Wp,
                                                   const float* __restrict__ bp,
                                                   float* __restrict__ out) {
  __shared__ __align__(16) bf16_t As[BM * BKK];
  __shared__ __align__(16) bf16_t Bs[BN * BKK];
  f32x4 acc[4][4];
#pragma unroll
  for (int i = 0; i < 4; i++)
#pragma unroll
    for (int j = 0; j < 4; j++) acc[i][j] = (f32x4){0.f, 0.f, 0.f, 0.f};
  const int n0 = blockIdx.x * BN, m0 = blockIdx.y * BM;
  gemm_mainloop(A, Wp, CH, m0, n0, As, Bs, acc);
  const int tid = threadIdx.x, lane = tid & 63, w = tid >> 6;
  const int quad = lane >> 4, l16 = lane & 15;
  const int wm = (w >> 1) << 6, wn = (w & 1) << 6;
  const int nbase = n0 + wn, mbase = m0 + wm;
#pragma unroll
  for (int mi = 0; mi < 4; mi++)
#pragma unroll
    for (int r = 0; r < 4; r++) {
      int m = mbase + mi * 16 + quad * 4 + r;
#pragma unroll
      for (int ni = 0; ni < 4; ni++) {
        int n = nbase + ni * 16 + l16;
        out[(size_t)m * CH + n] = acc[mi][ni][r] + bp[n];
      }
    }
}

extern "C" void kernel_launch(void* const* d_in, const int* in_sizes, int n_in,
                              void* d_out, int out_size, void* d_ws, size_t ws_size,
                              hipStream_t stream) {
  const float* x      = (const float*)d_in[0];
  const float* w_attn = (const float*)d_in[1];
  const float* b_attn = (const float*)d_in[2];
  const float* w_proj = (const float*)d_in[3];
  const float* b_proj = (const float*)d_in[4];
  const float* cosT   = (const float*)d_in[5];
  const float* sinT   = (const float*)d_in[6];
  float* out = (float*)d_out;

  bf16_t* xbf  = (bf16_t*)d_ws;
  bf16_t* wabf = xbf + (size_t)8192 * 1024;
  bf16_t* wpbf = wabf + (size_t)3072 * 1024;
  bf16_t* Qb   = wpbf + (size_t)1024 * 1024;
  bf16_t* Kb   = Qb + (size_t)8388608;
  bf16_t* VTb  = Kb + (size_t)8388608;
  bf16_t* attb = VTb + (size_t)8388608;

  cvt_kernel<<<8192, 256, 0, stream>>>((const float4*)x, (ushort4*)xbf, 2097152);
  cvt_kernel<<<3072, 256, 0, stream>>>((const float4*)w_attn, (ushort4*)wabf, 786432);
  cvt_kernel<<<1024, 256, 0, stream>>>((const float4*)w_proj, (ushort4*)wpbf, 262144);
  qkv_rope_kernel<<<dim3(24, 64), 256, 0, stream>>>(xbf, wabf, b_attn, cosT, sinT,
                                                    Qb, Kb, VTb);
  flash_kernel<<<dim3(16, 64), 256, 0, stream>>>(Qb, Kb, VTb, attb);
  proj_kernel<<<dim3(8, 64), 256, 0, stream>>>(attb, wpbf, b_proj, out);
}

// Round 4
// 310.717 us; speedup vs baseline: 2.1192x; 1.4747x over previous
//
#include <hip/hip_runtime.h>

typedef __bf16 bf16_t;
typedef bf16_t bf16x8 __attribute__((ext_vector_type(8)));
typedef bf16_t bf16x4 __attribute__((ext_vector_type(4)));
typedef float f32x4 __attribute__((ext_vector_type(4)));

constexpr int BATCH = 4, SEQ = 2048, CH = 1024, NHEAD = 16, HD = 64;
constexpr int BM = 128, BN = 128, BKK = 32;

// HW wait + compiler reorder barrier (builtin is IntrNoMem -> unsafe for ordering)
#define LGKM_FENCE() __asm__ __volatile__("s_waitcnt lgkmcnt(0)" ::: "memory")
#define VM_FENCE() __asm__ __volatile__("s_waitcnt vmcnt(0)" ::: "memory")

__device__ __forceinline__ void g2lds16(const bf16_t* g, bf16_t* l) {
  __builtin_amdgcn_global_load_lds((__attribute__((address_space(1))) void*)(g),
                                   (__attribute__((address_space(3))) void*)(l),
                                   16, 0, 0);
}

__device__ __forceinline__ f32x4 mfma16(bf16x8 a, bf16x8 b, f32x4 c) {
  return __builtin_amdgcn_mfma_f32_16x16x32_bf16(a, b, c, 0, 0, 0);
}

// ---------------- fp32 -> bf16 conversion ----------------
__global__ __launch_bounds__(256) void cvt_kernel(const float4* __restrict__ src,
                                                  ushort4* __restrict__ dst, int n4) {
  int i = blockIdx.x * 256 + threadIdx.x;
  if (i >= n4) return;
  float4 f = src[i];
  ushort4 o;
  o.x = __builtin_bit_cast(unsigned short, (bf16_t)f.x);
  o.y = __builtin_bit_cast(unsigned short, (bf16_t)f.y);
  o.z = __builtin_bit_cast(unsigned short, (bf16_t)f.z);
  o.w = __builtin_bit_cast(unsigned short, (bf16_t)f.w);
  dst[i] = o;
}

// ---------------- shared GEMM mainloop (C = A * W^T), m97 pattern ----------------
__device__ __forceinline__ void gemm_mainloop(const bf16_t* __restrict__ A,
                                              const bf16_t* __restrict__ W, int Kdim,
                                              int m0, int n0,
                                              bf16_t* As, bf16_t* Bs,
                                              f32x4 acc[4][4]) {
  const int tid = threadIdx.x;
  const int lane = tid & 63, w = tid >> 6;
  const int quad = lane >> 4, l16 = lane & 15;
  const int wm = (w >> 1) << 6, wn = (w & 1) << 6;
  const int srow = (w << 5) + (lane >> 2);
  const int scol = (lane & 3) << 3;
  const bf16_t* ga0 = A + (size_t)(m0 + srow) * Kdim + scol;
  const bf16_t* ga1 = A + (size_t)(m0 + srow + 16) * Kdim + scol;
  const bf16_t* gb0 = W + (size_t)(n0 + srow) * Kdim + scol;
  const bf16_t* gb1 = W + (size_t)(n0 + srow + 16) * Kdim + scol;
  bf16_t* la0 = As + srow * BKK + scol;
  bf16_t* la1 = As + (srow + 16) * BKK + scol;
  bf16_t* lb0 = Bs + srow * BKK + scol;
  bf16_t* lb1 = Bs + (srow + 16) * BKK + scol;
  for (int k0 = 0; k0 < Kdim; k0 += BKK) {
    g2lds16(ga0 + k0, la0);
    g2lds16(ga1 + k0, la1);
    g2lds16(gb0 + k0, lb0);
    g2lds16(gb1 + k0, lb1);
    VM_FENCE();           // explicit DMA drain before publish (LDS-DMA@barrier gap)
    __syncthreads();
    bf16x8 av[4], bv[4];
#pragma unroll
    for (int i = 0; i < 4; i++)
      av[i] = *(const bf16x8*)&As[(wm + i * 16 + l16) * BKK + quad * 8];
#pragma unroll
    for (int i = 0; i < 4; i++)
      bv[i] = *(const bf16x8*)&Bs[(wn + i * 16 + l16) * BKK + quad * 8];
#pragma unroll
    for (int mi = 0; mi < 4; mi++)
#pragma unroll
      for (int ni = 0; ni < 4; ni++)
        acc[mi][ni] = mfma16(av[mi], bv[ni], acc[mi][ni]);
    __syncthreads();
  }
}

// ---------------- QKV GEMM + bias + RoPE + scatter ----------------
__global__ __launch_bounds__(256) void qkv_rope_kernel(
    const bf16_t* __restrict__ X, const bf16_t* __restrict__ Wa,
    const float* __restrict__ ba, const float* __restrict__ cosT,
    const float* __restrict__ sinT, bf16_t* __restrict__ Q,
    bf16_t* __restrict__ Ko, bf16_t* __restrict__ VT) {
  constexpr int TSTRIDE = 68;
  __shared__ __align__(16) char smem[4 * 64 * TSTRIDE * 2];
  bf16_t* As = (bf16_t*)smem;
  bf16_t* Bs = As + BM * BKK;

  f32x4 acc[4][4];
#pragma unroll
  for (int i = 0; i < 4; i++)
#pragma unroll
    for (int j = 0; j < 4; j++) acc[i][j] = (f32x4){0.f, 0.f, 0.f, 0.f};

  const int n0 = blockIdx.x * BN, m0 = blockIdx.y * BM;
  gemm_mainloop(X, Wa, CH, m0, n0, As, Bs, acc);

  const int tid = threadIdx.x, lane = tid & 63, w = tid >> 6;
  const int quad = lane >> 4, l16 = lane & 15;
  const int wm = (w >> 1) << 6, wn = (w & 1) << 6;
  const int nbase = n0 + wn;
  const int part = nbase >> 10;
  const int h = (nbase & 1023) >> 6;
  const int mbase = m0 + wm;
  const int bb = mbase >> 11;
  const size_t headbase = ((size_t)(bb * NHEAD + h)) * SEQ * HD;

  if (part < 2) {
    bf16_t* O = (part == 0) ? Q : Ko;
#pragma unroll
    for (int mi = 0; mi < 4; mi++)
#pragma unroll
      for (int r = 0; r < 4; r++) {
        int m = mbase + mi * 16 + quad * 4 + r;
        int t = m & (SEQ - 1);
        const float* cr = cosT + t * HD;
        const float* sr = sinT + t * HD;
        size_t rowo = headbase + (size_t)t * HD;
#pragma unroll
        for (int ni = 0; ni < 2; ni++) {
          int d0 = ni * 16 + l16, d1 = d0 + 32;
          float v0 = acc[mi][ni][r] + ba[nbase + d0];
          float v1 = acc[mi][ni + 2][r] + ba[nbase + d1];
          float r0 = v0 * cr[d0] - v1 * sr[d0];
          float r1 = v1 * cr[d1] + v0 * sr[d1];
          O[rowo + d0] = (bf16_t)r0;
          O[rowo + d1] = (bf16_t)r1;
        }
      }
  } else {
    bf16_t* tb = (bf16_t*)smem + w * 64 * TSTRIDE;
    int t0 = mbase & (SEQ - 1);
#pragma unroll
    for (int mi = 0; mi < 4; mi++)
#pragma unroll
      for (int ni = 0; ni < 4; ni++) {
        int d = ni * 16 + l16;
        float bias = ba[nbase + d];
#pragma unroll
        for (int r = 0; r < 4; r++) {
          float v = acc[mi][ni][r] + bias;
          tb[d * TSTRIDE + mi * 16 + quad * 4 + r] = (bf16_t)v;
        }
      }
    LGKM_FENCE();  // same-wave LDS RAW, compiler-visible
    int half = lane >> 5, l5 = lane & 31;
    size_t vbase = ((size_t)(bb * NHEAD + h)) * HD * SEQ;
#pragma unroll
    for (int it = 0; it < 32; it++) {
      int d = it * 2 + half;
      unsigned int val = *(const unsigned int*)&tb[d * TSTRIDE + l5 * 2];
      *(unsigned int*)&VT[vbase + (size_t)d * SEQ + t0 + l5 * 2] = val;
    }
  }
}

// ---------------- flash attention v3: S^T orientation, paired q-tiles ----------------
constexpr int PS = 80;                          // P tile row stride (elements)
constexpr float SCL = 0.125f * 1.44269504089f;  // 1/sqrt(64) * log2(e)

// S^T C-layout: lane (quad,l16) holds key=ni*16+quad*4+r, q=l16.
__device__ __forceinline__ void sm_update(f32x4 (&s)[4], float& mr, float& lr,
                                          f32x4 (&y)[4], bf16_t* Prow,
                                          bool domask, int lim) {
  if (domask) {
#pragma unroll
    for (int ni = 0; ni < 4; ni++)
#pragma unroll
      for (int r = 0; r < 4; r++)
        if (ni * 16 + r > lim) s[ni][r] = -1e30f;
  }
  f32x4 mx;
#pragma unroll
  for (int r = 0; r < 4; r++)
    mx[r] = fmaxf(fmaxf(s[0][r], s[1][r]), fmaxf(s[2][r], s[3][r]));
  float cm = fmaxf(fmaxf(mx[0], mx[1]), fmaxf(mx[2], mx[3]));
  cm = fmaxf(cm, __shfl_xor(cm, 16));
  cm = fmaxf(cm, __shfl_xor(cm, 32));
  float mn = fmaxf(mr, cm);
  float hof = -SCL * mn;
  float al = __builtin_exp2f(fmaf(mr, SCL, hof));
  mr = mn;
  float sum = 0.f;
#pragma unroll
  for (int ni = 0; ni < 4; ni++) {
    float p0 = __builtin_exp2f(fmaf(s[ni][0], SCL, hof));
    float p1 = __builtin_exp2f(fmaf(s[ni][1], SCL, hof));
    float p2 = __builtin_exp2f(fmaf(s[ni][2], SCL, hof));
    float p3 = __builtin_exp2f(fmaf(s[ni][3], SCL, hof));
    bf16x4 pk = {(bf16_t)p0, (bf16_t)p1, (bf16_t)p2, (bf16_t)p3};
    *(bf16x4*)&Prow[ni * 16] = pk;
    sum += (p0 + p1) + (p2 + p3);
  }
  lr = fmaf(lr, al, sum);
#pragma unroll
  for (int ni = 0; ni < 4; ni++) y[ni] *= al;
}

__global__ __launch_bounds__(256) void flash_kernel(const bf16_t* __restrict__ Q,
                                                    const bf16_t* __restrict__ Kg,
                                                    const bf16_t* __restrict__ VT,
                                                    bf16_t* __restrict__ att) {
  __shared__ __align__(16) bf16_t Ks[2][64 * 64];
  __shared__ __align__(16) bf16_t Vs[2][64 * 64];
  __shared__ __align__(16) bf16_t Pt[8][16 * PS];
  const int tid = threadIdx.x, w = tid >> 6, lane = tid & 63;
  const int quad = lane >> 4, l16 = lane & 15;
  const int bh = blockIdx.y;
  const bf16_t* Qp = Q + (size_t)bh * SEQ * HD;
  const bf16_t* Kb = Kg + (size_t)bh * SEQ * HD;
  const bf16_t* Vb = VT + (size_t)bh * HD * SEQ;
  const int grow = lane >> 3;
  const int gj8 = ((lane & 7) ^ grow) * 8;
  const int i0 = w * 2;
  const int sw = l16 & 7;
  const int bloc = bh >> 4, hh = bh & 15;
  bf16_t* PA = &Pt[w * 2 + 0][l16 * PS + quad * 4];
  bf16_t* PB = &Pt[w * 2 + 1][l16 * PS + quad * 4];
  const bf16_t* PAr = &Pt[w * 2 + 0][l16 * PS + quad * 8];
  const bf16_t* PBr = &Pt[w * 2 + 1][l16 * PS + quad * 8];

  auto stage = [&](int kcs, int b) {
#pragma unroll
    for (int ii = 0; ii < 2; ii++) {
      int i = i0 + ii;
      g2lds16(Kb + (size_t)(kcs + i * 8 + grow) * HD + gj8, &Ks[b][(i * 64 + lane) * 8]);
      g2lds16(Vb + (size_t)(i * 8 + grow) * SEQ + kcs + gj8, &Vs[b][(i * 64 + lane) * 8]);
    }
  };

  for (int sp = 0; sp < 2; ++sp) {
    const int qb = sp ? (int)blockIdx.x : 15 - (int)blockIdx.x;  // pair (15-p, p)
    const int q0 = qb * 128;
    const int mA = q0 + w * 16, mB = mA + 64;
    bf16x8 aqA0 = *(const bf16x8*)&Qp[(size_t)(mA + l16) * HD + quad * 8];
    bf16x8 aqA1 = *(const bf16x8*)&Qp[(size_t)(mA + l16) * HD + 32 + quad * 8];
    bf16x8 aqB0 = *(const bf16x8*)&Qp[(size_t)(mB + l16) * HD + quad * 8];
    bf16x8 aqB1 = *(const bf16x8*)&Qp[(size_t)(mB + l16) * HD + 32 + quad * 8];
    float mrA = -1e30f, lrA = 0.f, mrB = -1e30f, lrB = 0.f;
    f32x4 yA[4], yB[4];
#pragma unroll
    for (int ni = 0; ni < 4; ni++) {
      yA[ni] = (f32x4){0.f, 0.f, 0.f, 0.f};
      yB[ni] = (f32x4){0.f, 0.f, 0.f, 0.f};
    }
    const int nch = 2 * qb + 2;

    stage(0, 0);
    VM_FENCE();
    __syncthreads();

    for (int c = 0; c < nch; ++c) {
      const int kc = c * 64, buf = c & 1;
      if (c + 1 < nch) stage(kc + 64, buf ^ 1);
      const bool doA = (c + 1 < nch);  // wave-uniform: all chunks except last
      f32x4 sA[4], sB[4];
#pragma unroll
      for (int ni = 0; ni < 4; ni++) {
        bf16x8 k0 = *(const bf16x8*)&Ks[buf][((ni * 16 + l16) * 8 + (quad ^ sw)) * 8];
        bf16x8 k1 = *(const bf16x8*)&Ks[buf][((ni * 16 + l16) * 8 + ((4 + quad) ^ sw)) * 8];
        f32x4 z = (f32x4){0.f, 0.f, 0.f, 0.f};
        sB[ni] = mfma16(k1, aqB1, mfma16(k0, aqB0, z));
        if (doA) sA[ni] = mfma16(k1, aqA1, mfma16(k0, aqA0, z));
      }
      sm_update(sB, mrB, lrB, yB, PB, c == nch - 1, mB + l16 - kc - quad * 4);
      if (doA)
        sm_update(sA, mrA, lrA, yA, PA, c == nch - 2, mA + l16 - kc - quad * 4);
      LGKM_FENCE();  // own-wave P writes drained, compiler-visible
      bf16x8 pB0 = *(const bf16x8*)&PBr[0];
      bf16x8 pB1 = *(const bf16x8*)&PBr[32];
      bf16x8 pA0, pA1;
      if (doA) {
        pA0 = *(const bf16x8*)&PAr[0];
        pA1 = *(const bf16x8*)&PAr[32];
      }
#pragma unroll
      for (int ni = 0; ni < 4; ni++) {
        bf16x8 v0 = *(const bf16x8*)&Vs[buf][((ni * 16 + l16) * 8 + (quad ^ sw)) * 8];
        bf16x8 v1 = *(const bf16x8*)&Vs[buf][((ni * 16 + l16) * 8 + ((4 + quad) ^ sw)) * 8];
        yB[ni] = mfma16(v1, pB1, mfma16(v0, pB0, yB[ni]));
        if (doA) yA[ni] = mfma16(v1, pA1, mfma16(v0, pA0, yA[ni]));
      }
      VM_FENCE();  // prefetch DMA drained before publishing buffers
      __syncthreads();
    }

    // epilogue: y^T[d][q], d = ni*16+quad*4+r, q = l16
    lrA += __shfl_xor(lrA, 16);
    lrA += __shfl_xor(lrA, 32);
    lrB += __shfl_xor(lrB, 16);
    lrB += __shfl_xor(lrB, 32);
    float invA = 1.f / lrA, invB = 1.f / lrB;
    size_t rbA = ((size_t)bloc * SEQ + mA + l16) * CH + hh * HD + quad * 4;
    size_t rbB = ((size_t)bloc * SEQ + mB + l16) * CH + hh * HD + quad * 4;
#pragma unroll
    for (int ni = 0; ni < 4; ni++) {
      bf16x4 oA = {(bf16_t)(yA[ni][0] * invA), (bf16_t)(yA[ni][1] * invA),
                   (bf16_t)(yA[ni][2] * invA), (bf16_t)(yA[ni][3] * invA)};
      bf16x4 oB = {(bf16_t)(yB[ni][0] * invB), (bf16_t)(yB[ni][1] * invB),
                   (bf16_t)(yB[ni][2] * invB), (bf16_t)(yB[ni][3] * invB)};
      *(bf16x4*)&att[rbA + ni * 16] = oA;
      *(bf16x4*)&att[rbB + ni * 16] = oB;
    }
  }
}

// ---------------- output projection GEMM ----------------
__global__ __launch_bounds__(256) void proj_kernel(const bf16_t* __restrict__ A,
                                                   const bf16_t* __restrict__ Wp,
                                                   const float* __restrict__ bp,
                                                   float* __restrict__ out) {
  __shared__ __align__(16) bf16_t As[BM * BKK];
  __shared__ __align__(16) bf16_t Bs[BN * BKK];
  f32x4 acc[4][4];
#pragma unroll
  for (int i = 0; i < 4; i++)
#pragma unroll
    for (int j = 0; j < 4; j++) acc[i][j] = (f32x4){0.f, 0.f, 0.f, 0.f};
  const int n0 = blockIdx.x * BN, m0 = blockIdx.y * BM;
  gemm_mainloop(A, Wp, CH, m0, n0, As, Bs, acc);
  const int tid = threadIdx.x, lane = tid & 63, w = tid >> 6;
  const int quad = lane >> 4, l16 = lane & 15;
  const int wm = (w >> 1) << 6, wn = (w & 1) << 6;
  const int nbase = n0 + wn, mbase = m0 + wm;
#pragma unroll
  for (int mi = 0; mi < 4; mi++)
#pragma unroll
    for (int r = 0; r < 4; r++) {
      int m = mbase + mi * 16 + quad * 4 + r;
#pragma unroll
      for (int ni = 0; ni < 4; ni++) {
        int n = nbase + ni * 16 + l16;
        out[(size_t)m * CH + n] = acc[mi][ni][r] + bp[n];
      }
    }
}

extern "C" void kernel_launch(void* const* d_in, const int* in_sizes, int n_in,
                              void* d_out, int out_size, void* d_ws, size_t ws_size,
                              hipStream_t stream) {
  const float* x      = (const float*)d_in[0];
  const float* w_attn = (const float*)d_in[1];
  const float* b_attn = (const float*)d_in[2];
  const float* w_proj = (const float*)d_in[3];
  const float* b_proj = (const float*)d_in[4];
  const float* cosT   = (const float*)d_in[5];
  const float* sinT   = (const float*)d_in[6];
  float* out = (float*)d_out;

  bf16_t* xbf  = (bf16_t*)d_ws;
  bf16_t* wabf = xbf + (size_t)8192 * 1024;
  bf16_t* wpbf = wabf + (size_t)3072 * 1024;
  bf16_t* Qb   = wpbf + (size_t)1024 * 1024;
  bf16_t* Kb   = Qb + (size_t)8388608;
  bf16_t* VTb  = Kb + (size_t)8388608;
  bf16_t* attb = VTb + (size_t)8388608;

  cvt_kernel<<<8192, 256, 0, stream>>>((const float4*)x, (ushort4*)xbf, 2097152);
  cvt_kernel<<<3072, 256, 0, stream>>>((const float4*)w_attn, (ushort4*)wabf, 786432);
  cvt_kernel<<<1024, 256, 0, stream>>>((const float4*)w_proj, (ushort4*)wpbf, 262144);
  qkv_rope_kernel<<<dim3(24, 64), 256, 0, stream>>>(xbf, wabf, b_attn, cosT, sinT,
                                                    Qb, Kb, VTb);
  flash_kernel<<<dim3(8, 64), 256, 0, stream>>>(Qb, Kb, VTb, attb);
  proj_kernel<<<dim3(8, 64), 256, 0, stream>>>(attb, wpbf, b_proj, out);
}